// Round 7
// baseline (285.147 us; speedup 1.0000x reference)
//
#include <hip/hip_runtime.h>
#include <math.h>

#define HEADS 12
#define DH    64
#define Dm    768
#define I3    2304
#define Nn    1024
#define Mm    4096
#define BHt   48
#define LOG2E 1.4426950408889634f

// minmax pair indices
#define P_X  0
#define P_W1 1
#define P_Q  2
#define P_K  3
#define P_V  4
#define P_A  5
#define P_O  6
#define P_W2 7

typedef int   v4i __attribute__((ext_vector_type(4)));
typedef float v4f __attribute__((ext_vector_type(4)));

#if __has_builtin(__builtin_amdgcn_exp2f)
#define EXP2(x) __builtin_amdgcn_exp2f(x)
#else
#define EXP2(x) exp2f(x)
#endif

// ---------- helpers ----------
__device__ inline unsigned encf(float f) {
    unsigned u = __float_as_uint(f);
    return (u & 0x80000000u) ? ~u : (u | 0x80000000u);
}
__device__ inline float decf(unsigned u) {
    return (u & 0x80000000u) ? __uint_as_float(u & 0x7fffffffu) : __uint_as_float(~u);
}
__device__ inline void get_sz(const unsigned* scal, int pair, float* s, float* z) {
    float mn = decf(scal[2 * pair]);
    float mx = decf(scal[2 * pair + 1]);
    float ss = (mx - mn) / 15.0f;
    *s = ss;
    *z = rintf(15.0f - mx / ss);
}

// XCD head-clustering swizzle, 32 blocks/head (split-j grid): dispatch round-robins
// XCD = blk % 8; all 32 blocks of a head land on ONE XCD (6 heads x 32 blocks per XCD).
// K/V fetched from HBM once per chip, L2 hits thereafter (FETCH 27->5 MB, measured r5).
__device__ inline void swz_bh32(int blk, int* bh, int* itile) {
    int xcd = blk & 7, idx = blk >> 3;
    *itile = idx & 31;                 // 32-row tile index
    *bh = xcd + 8 * (idx >> 5);
}

// ---------- kernels ----------
// init scal + zero rowsum_xqkv (4096) and colsum_vq (3072)
__global__ __launch_bounds__(256) void k_init(unsigned* scal, float* z1, int n1, float* z2, int n2) {
    int g = blockIdx.x * 256 + threadIdx.x;
    if (g < n1) z1[g] = 0.f;
    if (g < n2) z2[g] = 0.f;
    if (g < 8) { scal[2 * g] = 0xFFFFFFFFu; scal[2 * g + 1] = 0u; }
}

// fused minmax of x (4096x768), w_qkv (2304x768), w_out (768x768); all cols=768
__global__ __launch_bounds__(256) void k_minmax3(const float* x, const float* w1, const float* w2,
                                                 unsigned* scal) {
    __shared__ float rmn[256], rmx[256];
    int bid = blockIdx.x, tid = threadIdx.x;
    const float* src; int rows, pair, b0, nb;
    if (bid < 256)      { src = x;  rows = 4096; pair = P_X;  b0 = 0;   nb = 256; }
    else if (bid < 384) { src = w1; rows = 2304; pair = P_W1; b0 = 256; nb = 128; }
    else                { src = w2; rows = 768;  pair = P_W2; b0 = 384; nb = 64;  }
    float mn = INFINITY, mx = -INFINITY;
    for (int r = bid - b0; r < rows; r += nb) {
        const float* row = src + (long)r * 768;
#pragma unroll
        for (int k = 0; k < 3; ++k) {
            float v = row[tid + k * 256];
            mn = fminf(mn, v); mx = fmaxf(mx, v);
        }
    }
    rmn[tid] = mn; rmx[tid] = mx; __syncthreads();
    for (int s = 128; s > 0; s >>= 1) {
        if (tid < s) { rmn[tid] = fminf(rmn[tid], rmn[tid + s]); rmx[tid] = fmaxf(rmx[tid], rmx[tid + s]); }
        __syncthreads();
    }
    if (tid == 0) {
        atomicMin(&scal[2 * pair], encf(rmn[0]));
        atomicMax(&scal[2 * pair + 1], encf(rmx[0]));
    }
}

// fused quantization of x / w_qkv / w_out (cols=768) -> int8 + row sums
__global__ __launch_bounds__(256) void k_quant3(const float* x, const float* w1, const float* w2,
                                                const unsigned* scal,
                                                signed char* xq, signed char* wq, signed char* w2q,
                                                float* rs_x, float* rs_w1, float* rs_w2) {
    __shared__ float red[256];
    int bid = blockIdx.x, tid = threadIdx.x;
    const float* src; signed char* dq; float* rs; int pair, r;
    if (bid < 4096)      { src = x;  dq = xq;  rs = rs_x;  pair = P_X;  r = bid; }
    else if (bid < 6400) { src = w1; dq = wq;  rs = rs_w1; pair = P_W1; r = bid - 4096; }
    else                 { src = w2; dq = w2q; rs = rs_w2; pair = P_W2; r = bid - 6400; }
    float s, z; get_sz(scal, pair, &s, &z);
    const float* row = src + (long)r * 768;
    signed char* drow = dq + (long)r * 768;
    float acc = 0.f;
#pragma unroll
    for (int k = 0; k < 3; ++k) {
        int c = tid + k * 256;
        float q = rintf(row[c] / s + z);
        drow[c] = (signed char)(int)q;
        acc += q;
    }
    red[tid] = acc; __syncthreads();
    for (int s2 = 128; s2 > 0; s2 >>= 1) { if (tid < s2) red[tid] += red[tid + s2]; __syncthreads(); }
    if (tid == 0) rs[r] = red[0];
}

// single-array quant (for out_mat -> oq), cols=768. NOTE: no row sums — GEMM2's row
// correction uses rowsum_xqkv (faithful reference bug), oq row sums are never needed.
__global__ __launch_bounds__(256) void k_quant_rows(const float* src, const unsigned* scal, int pair,
                                                    signed char* dq) {
    int r = blockIdx.x, tid = threadIdx.x;
    float s, z; get_sz(scal, pair, &s, &z);
    const float* row = src + (long)r * 768;
    signed char* drow = dq + (long)r * 768;
#pragma unroll
    for (int k = 0; k < 3; ++k) {
        int c = tid + k * 256;
        float q = rintf(row[c] / s + z);
        drow[c] = (signed char)(int)q;
    }
}

// MFMA int8 GEMM, block tile 128x128, BK=64 bytes, LDS-staged with register double-buffer.
__global__ __launch_bounds__(256) void k_gemm_mfma(const signed char* A, const signed char* B,
                                                   const float* colsumB, const float* rowsumA,
                                                   const float* bias, float* C, int K, int ldC,
                                                   const unsigned* scal, int pairA, int pairB,
                                                   float corrK, int do_stats, float* rowsum_out,
                                                   unsigned* scal_mm) {
    __shared__ __align__(16) signed char As[128 * 64];
    __shared__ __align__(16) signed char Bs[128 * 64];
    __shared__ float red[256];
    int tid = threadIdx.x;
    int wave = tid >> 6, lane = tid & 63;
    int col16 = lane & 15, quad = lane >> 4;
    long rowbase = (long)blockIdx.y * 128;
    long colbase = (long)blockIdx.x * 128;

    int c4 = tid & 3, r4 = tid >> 2;
    const signed char* ag0 = A + (rowbase + r4) * K + c4 * 16;
    const signed char* ag1 = A + (rowbase + r4 + 64) * K + c4 * 16;
    const signed char* bg0 = B + (colbase + r4) * K + c4 * 16;
    const signed char* bg1 = B + (colbase + r4 + 64) * K + c4 * 16;
    int soff0 = ((r4 >> 4) << 10) + (c4 << 8) + ((r4 & 15) << 4);
    int soff1 = soff0 + 4096;

    v4i ra0 = *(const v4i*)ag0;
    v4i ra1 = *(const v4i*)ag1;
    v4i rb0 = *(const v4i*)bg0;
    v4i rb1 = *(const v4i*)bg1;

    const int afrag_off = wave * 2048 + quad * 256 + col16 * 16;
    const int bfrag_off = quad * 256 + col16 * 16;
    v4i acc[2][8] = {};
    int nk = K >> 6;
    for (int kt = 0; kt < nk; ++kt) {
        *(v4i*)(As + soff0) = ra0;
        *(v4i*)(As + soff1) = ra1;
        *(v4i*)(Bs + soff0) = rb0;
        *(v4i*)(Bs + soff1) = rb1;
        __syncthreads();
        if (kt + 1 < nk) {
            int ko = (kt + 1) << 6;
            ra0 = *(const v4i*)(ag0 + ko);
            ra1 = *(const v4i*)(ag1 + ko);
            rb0 = *(const v4i*)(bg0 + ko);
            rb1 = *(const v4i*)(bg1 + ko);
        }
        v4i af0 = *(const v4i*)(As + afrag_off);
        v4i af1 = *(const v4i*)(As + afrag_off + 1024);
        v4i bf[8];
#pragma unroll
        for (int g = 0; g < 8; ++g) bf[g] = *(const v4i*)(Bs + bfrag_off + g * 1024);
#pragma unroll
        for (int g = 0; g < 8; ++g) {
            acc[0][g] = __builtin_amdgcn_mfma_i32_16x16x64_i8(af0, bf[g], acc[0][g], 0, 0, 0);
            acc[1][g] = __builtin_amdgcn_mfma_i32_16x16x64_i8(af1, bf[g], acc[1][g], 0, 0, 0);
        }
        __syncthreads();
    }

    float sA, zA, sB, zB;
    get_sz(scal, pairA, &sA, &zA);
    get_sz(scal, pairB, &sB, &zB);
    float sAB = sA * sB;
    float zz = (zA * zB) * corrK;
    float vmn = INFINITY, vmx = -INFINITY;
    float rowpart[2][4] = {};
#pragma unroll
    for (int i2 = 0; i2 < 2; ++i2)
#pragma unroll
        for (int g = 0; g < 8; ++g) {
            long col = colbase + g * 16 + col16;
            float cs = colsumB[col] * zA;
            float bv = bias ? bias[col] : 0.f;
#pragma unroll
            for (int r = 0; r < 4; ++r) {
                long row = rowbase + wave * 32 + i2 * 16 + quad * 4 + r;
                float v = ((float)acc[i2][g][r] - cs - rowsumA[row] * zB + zz) * sAB + bv;
                C[row * ldC + col] = v;
                rowpart[i2][r] += v;
                vmn = fminf(vmn, v); vmx = fmaxf(vmx, v);
            }
        }
    if (do_stats) {
#pragma unroll
        for (int i2 = 0; i2 < 2; ++i2)
#pragma unroll
            for (int r = 0; r < 4; ++r) {
                float s = rowpart[i2][r];
                s += __shfl_xor(s, 1); s += __shfl_xor(s, 2);
                s += __shfl_xor(s, 4); s += __shfl_xor(s, 8);
                if (col16 == 0)
                    atomicAdd(&rowsum_out[rowbase + wave * 32 + i2 * 16 + quad * 4 + r], s);
            }
        int pair = P_Q + (int)(colbase / 768);
        red[tid] = vmx; __syncthreads();
        for (int s = 128; s > 0; s >>= 1) { if (tid < s) red[tid] = fmaxf(red[tid], red[tid + s]); __syncthreads(); }
        if (tid == 0) atomicMax(&scal_mm[2 * pair + 1], encf(red[0]));
        __syncthreads();
        red[tid] = vmn; __syncthreads();
        for (int s = 128; s > 0; s >>= 1) { if (tid < s) red[tid] = fminf(red[tid], red[tid + s]); __syncthreads(); }
        if (tid == 0) atomicMin(&scal_mm[2 * pair], encf(red[0]));
    }
}

// quantize q/k/v, 64 i-rows per block. qq,kq row-contig; vqT via LDS transpose (16B stores).
// cskc[j] = colsum_kq[j]*zq*csc*LOG2E (log2-domain constant), colsum_vq via exact atomicAdd.
__global__ __launch_bounds__(256) void k_quant_qkv2(const float* xqkv, const unsigned* scal,
                                                    signed char* qq, signed char* kq, signed char* vqT,
                                                    float* rowsum_qq, float* cskc, float* colsum_vq) {
    __shared__ __align__(16) signed char vt[64 * 80];   // [d][i_local], stride 80
    __shared__ float vred[4][64];
    int blk = blockIdx.x;
    int bh = blk >> 4, itile = blk & 15;
    int tid = threadIdx.x;
    int wave = tid >> 6, d = tid & 63;
    int b = bh / HEADS, h = bh - HEADS * b;
    float sq, zq, sk, zk, sv, zv;
    get_sz(scal, P_Q, &sq, &zq);
    get_sz(scal, P_K, &sk, &zk);
    get_sz(scal, P_V, &sv, &zv);
    float zqcsc2 = zq * ((0.125f * sq) * sk) * LOG2E;
    int vb = 0;
    float vsum = 0.f;
    for (int ir = 0; ir < 16; ++ir) {
        int il = wave * 16 + ir;
        int i = itile * 64 + il;
        const float* row = xqkv + ((long)b * Nn + i) * I3 + h * DH;
        float q = rintf(row[d] / sq + zq);
        float k = rintf(row[768 + d] / sk + zk);
        float v = rintf(row[1536 + d] / sv + zv);
        long o = ((long)bh * Nn + i) * 64 + d;
        qq[o] = (signed char)(int)q;
        kq[o] = (signed char)(int)k;
        vsum += v;
        vb |= ((int)v & 0xff) << ((ir & 3) * 8);
        if ((ir & 3) == 3) {
            *(int*)(vt + d * 80 + (il & ~3)) = vb;
            vb = 0;
        }
        float s1 = q, s2 = k;
        for (int off = 32; off > 0; off >>= 1) {
            s1 += __shfl_down(s1, off);
            s2 += __shfl_down(s2, off);
        }
        if (d == 0) { rowsum_qq[bh * Nn + i] = s1; cskc[bh * Nn + i] = s2 * zqcsc2; }
    }
    vred[wave][d] = vsum;
    __syncthreads();
    int dd = tid >> 2, c = tid & 3;
    *(v4i*)(vqT + ((long)bh * 64 + dd) * 1024 + itile * 64 + c * 16) = *(const v4i*)(vt + dd * 80 + c * 16);
    if (tid < 64)   // exact: integer-valued floats, order-free
        atomicAdd(&colsum_vq[bh * 64 + tid],
                  ((vred[0][tid] + vred[1][tid]) + vred[2][tid]) + vred[3][tid]);
}

// Pass A v15: swapped-operand QK^T (r6) + SPLIT-J at 56 VGPR. Block = 32 q-rows,
// wave>>1 = row-group, wave&1 = j-half (8 chunks). Grid BHt*32 = 1536 blocks ->
// 24 waves/CU structural (was 12; total waves is grid-limited, r1-r6 ablation).
// Wave-pair merge of (m, se, lmin) via LDS with the log2-domain combine.
__global__ __launch_bounds__(256) void k_attn_a8(const signed char* qq, const signed char* kq,
                                                 const float* rowsum_qq, const float* cskc,
                                                 unsigned* scal, float* rowmax, float* sumexp) {
    __shared__ float red[256];
    __shared__ float Mj[2][64], Sj[2][64], Lj[2][64];
    int bh, itile;
    swz_bh32(blockIdx.x, &bh, &itile);
    int tid = threadIdx.x;
    int wave = tid >> 6, lane = tid & 63;
    int col16 = lane & 15, quad = lane >> 4;
    int rowbase = itile * 32 + (wave >> 1) * 16;
    int jhalf = wave & 1;
    int c0 = jhalf * 8;                        // this wave's chunks [c0, c0+8)
    const signed char* kbase = kq + (long)bh * Nn * 64;
    v4i qfrag = *(const v4i*)(qq + ((long)bh * Nn + rowbase + col16) * 64 + quad * 16);
    float sq, zq, sk, zk;
    get_sz(scal, P_Q, &sq, &zq);
    get_sz(scal, P_K, &sk, &zk);
    float csc2 = ((0.125f * sq) * sk) * LOG2E;
    int irow = bh * Nn + rowbase + col16;
    float roff = rowsum_qq[irow] * zk * csc2;
    v4i zero = {0, 0, 0, 0};
    float m[4]    = {-INFINITY, -INFINITY, -INFINITY, -INFINITY};
    float se[4]   = {0.f, 0.f, 0.f, 0.f};
    float lmin[4] = {INFINITY, INFINITY, INFINITY, INFINITY};
    const signed char* kf = kbase + (long)(c0 * 64 + col16) * 64 + quad * 16;
    const float* ckq = cskc + bh * Nn + c0 * 64 + quad * 4;
    v4i kb[2][4];
#pragma unroll
    for (int t = 0; t < 4; ++t)
        kb[0][t] = *(const v4i*)(kf + (long)(t * 16) * 64);
#pragma unroll 2
    for (int ch = 0; ch < 8; ++ch) {
        int cur = ch & 1, nxt = cur ^ 1;
        int pch = (ch < 7) ? ch + 1 : 7;
#pragma unroll
        for (int t = 0; t < 4; ++t)
            kb[nxt][t] = *(const v4i*)(kf + (long)(pch * 64 + t * 16) * 64);
#pragma unroll
        for (int s = 0; s < 4; ++s) {
            v4i d = __builtin_amdgcn_mfma_i32_16x16x64_i8(kb[cur][s], qfrag, zero, 0, 0, 0);
            v4f ck4 = *(const v4f*)(ckq + ch * 64 + s * 16);
#pragma unroll
            for (int r = 0; r < 4; ++r) {
                float dv = fmaf((float)d[r], csc2, -(ck4[r] + roff));
                lmin[r] = fminf(lmin[r], dv);
                float mn = fmaxf(m[r], dv);
                // single-EXP2 online update, bit-identical to:
                //   se = fmaf(se, EXP2(m-mn), EXP2(dv-mn))
                float e = EXP2(fminf(m[r], dv) - mn);
                se[r] = (dv > m[r]) ? fmaf(se[r], e, 1.0f) : (se[r] + e);
                m[r] = mn;
            }
        }
    }
    // in-lane merge of the 4 r-chains (same row, disjoint j-subsets)
    float mm = fmaxf(fmaxf(m[0], m[1]), fmaxf(m[2], m[3]));
    float seT = fmaf(se[0], EXP2(m[0] - mm),
               fmaf(se[1], EXP2(m[1] - mm),
               fmaf(se[2], EXP2(m[2] - mm), se[3] * EXP2(m[3] - mm))));
    float lmT = fminf(fminf(lmin[0], lmin[1]), fminf(lmin[2], lmin[3]));
    // cross-quad butterfly (lanes col16+16q all hold the same row)
#pragma unroll
    for (int off = 16; off <= 32; off <<= 1) {
        float mo = __shfl_xor(mm, off);
        float so = __shfl_xor(seT, off);
        float lo = __shfl_xor(lmT, off);
        float mn = fmaxf(mm, mo);
        seT = fmaf(seT, EXP2(mm - mn), so * EXP2(mo - mn));
        mm = mn;
        lmT = fminf(lmT, lo);
    }
    // cross-wave (j-half) merge via LDS
    if (jhalf) { Mj[wave >> 1][lane] = mm; Sj[wave >> 1][lane] = seT; Lj[wave >> 1][lane] = lmT; }
    __syncthreads();
    float amax_c = -INFINITY, amin_c = INFINITY;
    if (!jhalf) {
        int p = wave >> 1;
        float m2 = Mj[p][lane], s2 = Sj[p][lane], l2 = Lj[p][lane];
        float mn = fmaxf(mm, m2);
        seT = fmaf(seT, EXP2(mm - mn), s2 * EXP2(m2 - mn));
        mm = mn;
        lmT = fminf(lmT, l2);
        if (quad == 0) {
            rowmax[irow] = mm;        // log2 units
            sumexp[irow] = seT;
        }
        amax_c = 1.0f / seT;          // duplicates across quads: min/max idempotent
        amin_c = EXP2(lmT - mm) / seT;
    }
    red[tid] = amax_c; __syncthreads();
    for (int s = 128; s > 0; s >>= 1) { if (tid < s) red[tid] = fmaxf(red[tid], red[tid + s]); __syncthreads(); }
    if (tid == 0) atomicMax(&scal[2 * P_A + 1], encf(red[0]));
    __syncthreads();
    red[tid] = amin_c; __syncthreads();
    for (int s = 128; s > 0; s >>= 1) { if (tid < s) red[tid] = fminf(red[tid], red[tid + s]); __syncthreads(); }
    if (tid == 0) atomicMin(&scal[2 * P_A], encf(red[0]));
}

// Pass B v15: swapped-operand structure (r6) + SPLIT-J. Each wave runs 8 chunks
// (j-half); wave pairs merge accPV (int32, exact) + rs_a (integer-valued floats,
// exact) by REUSING AqB after a barrier -> LDS stays 9216 B, output bit-identical
// to unsplit. K register double-buffer prefetch (2-chunk distance) kept.
__global__ __launch_bounds__(256) void k_attn_b8(const signed char* qq, const signed char* kq,
                                                 const signed char* vqT, const float* rowsum_qq,
                                                 const float* cskc, const float* colsum_vq,
                                                 const float* rowmax, const float* sumexp,
                                                 unsigned* scal, float* out_mat) {
    __shared__ __align__(16) signed char AqB[8192];
    __shared__ float red[256];
    int bh, itile;
    swz_bh32(blockIdx.x, &bh, &itile);
    int tid = threadIdx.x;
    int wave = tid >> 6, lane = tid & 63;
    int col16 = lane & 15, quad = lane >> 4;
    int rowbase = itile * 32 + (wave >> 1) * 16;
    int jhalf = wave & 1;
    int c0 = jhalf * 8;                        // this wave's chunks [c0, c0+8)
    int b = bh / HEADS, h = bh - HEADS * b;
    const signed char* kbase = kq + (long)bh * Nn * 64;
    v4i qfrag = *(const v4i*)(qq + ((long)bh * Nn + rowbase + col16) * 64 + quad * 16);
    float sq, zq, sk, zk, sv, zv, sa, za;
    get_sz(scal, P_Q, &sq, &zq);
    get_sz(scal, P_K, &sk, &zk);
    get_sz(scal, P_V, &sv, &zv);
    get_sz(scal, P_A, &sa, &za);
    float csc2 = ((0.125f * sq) * sk) * LOG2E;
    int irow = bh * Nn + rowbase + col16;
    float roff = rowsum_qq[irow] * zk * csc2 + rowmax[irow];   // log2 units
    float crcp = 1.0f / (sumexp[irow] * sa);
    v4i accPV[4] = {};
    float rs_a = 0.f;
    v4i zero = {0, 0, 0, 0};
    const signed char* kf = kbase + (long)(c0 * 64 + col16) * 64 + quad * 16;
    const float* ckq = cskc + bh * Nn + c0 * 64 + quad * 4;
    const signed char* vbase = vqT + (long)bh * 64 * 1024 + c0 * 64;
    // LDS transpose: writer lane (c,q) puts pk[s] at s*256 + c*16 + q*4 (2 lanes/bank,
    // free); reader lane (c,q) takes b128 at q*256 + c*16. Per-wave private 1 KiB.
    const int wbase = wave * 1024 + col16 * 16 + quad * 4;
    const int rbase = wave * 1024 + quad * 256 + col16 * 16;

    // K-fragment double-buffer registers (local chunk c lives in buffer c&1)
    v4i kb0[4], kb1[4];
#pragma unroll
    for (int t = 0; t < 4; ++t) {
        kb0[t] = *(const v4i*)(kf + (long)(t * 16) * 64);
        kb1[t] = *(const v4i*)(kf + (long)(64 + t * 16) * 64);
    }

    // quantize local chunk CH into LDS buffer BUF using preloaded K frags KB.
#define QUANT_CHUNK(CH, BUF, KB)                                                        \
    {                                                                                   \
        _Pragma("unroll")                                                               \
        for (int s = 0; s < 4; ++s) {                                                   \
            v4i d = __builtin_amdgcn_mfma_i32_16x16x64_i8(KB[s], qfrag, zero, 0, 0, 0); \
            v4f ck4 = *(const v4f*)(ckq + (CH) * 64 + s * 16);                          \
            unsigned pks = 0;                                                           \
            _Pragma("unroll")                                                           \
            for (int r = 0; r < 4; ++r) {                                               \
                float es = fmaf((float)d[r], csc2, -(ck4[r] + roff));                   \
                float aqv = rintf(fmaf(EXP2(es), crcp, za));                            \
                rs_a += aqv;                                                            \
                pks |= ((unsigned)(int)aqv & 255u) << (8 * r);                          \
            }                                                                           \
            *(int*)(AqB + (BUF) * 4096 + wbase + s * 256) = (int)pks;                   \
        }                                                                               \
    }

    // one iteration: local chunk CH (buffer CUR). V loads for CH, prefetch K for CH+2
    // into CUR-parity K regs, quantize CH+1 into buffer 1-CUR, then PV for CH.
#define BODY(CH, CUR, KBc, KBn)                                                         \
    {                                                                                   \
        v4i pa = *(const v4i*)(AqB + (CUR) * 4096 + rbase);                             \
        v4i bv[4];                                                                      \
        _Pragma("unroll")                                                               \
        for (int g = 0; g < 4; ++g)                                                     \
            bv[g] = *(const v4i*)(vbase + (long)(g * 16 + col16) * 1024 + (CH) * 64 + quad * 16); \
        if ((CH) < 6) {                                                                 \
            _Pragma("unroll")                                                           \
            for (int t = 0; t < 4; ++t)                                                 \
                KBc[t] = *(const v4i*)(kf + (long)(((CH) + 2) * 64 + t * 16) * 64);     \
        }                                                                               \
        if ((CH) < 7) QUANT_CHUNK((CH) + 1, 1 - (CUR), KBn)                             \
        _Pragma("unroll")                                                               \
        for (int g = 0; g < 4; ++g)                                                     \
            accPV[g] = __builtin_amdgcn_mfma_i32_16x16x64_i8(bv[g], pa, accPV[g], 0, 0, 0); \
    }

    QUANT_CHUNK(0, 0, kb0)
    for (int ch2 = 0; ch2 < 4; ++ch2) {
        int ch = ch2 * 2;
        BODY(ch, 0, kb0, kb1)
        BODY(ch + 1, 1, kb1, kb0)
    }
#undef BODY
#undef QUANT_CHUNK

    // row sum of aq over this wave's j-half (integer-valued floats, order-free exact)
    rs_a += __shfl_xor(rs_a, 16);
    rs_a += __shfl_xor(rs_a, 32);

    // cross-wave (j-half) merge: exact. Reuse AqB (all quant traffic done after barrier).
    __syncthreads();
    if (jhalf) {
        int p = wave >> 1;
#pragma unroll
        for (int g = 0; g < 4; ++g)
            *(v4i*)(AqB + p * 4096 + g * 1024 + lane * 16) = accPV[g];
        red[p * 64 + lane] = rs_a;
    }
    __syncthreads();
    float vmn = INFINITY, vmx = -INFINITY;
    if (!jhalf) {
        int p = wave >> 1;
#pragma unroll
        for (int g = 0; g < 4; ++g) {
            v4i o = *(const v4i*)(AqB + p * 4096 + g * 1024 + lane * 16);
            accPV[g] += o;
        }
        rs_a += red[p * 64 + lane];

        float sav = sa * sv;
        float zz = (za * zv) * 1024.0f;
        long obase = ((long)b * Nn + rowbase + col16) * Dm + h * DH;
#pragma unroll
        for (int g = 0; g < 4; ++g) {
            int d4 = g * 16 + quad * 4;
            v4f cs4 = *(const v4f*)(colsum_vq + bh * 64 + d4);
            v4f ov;
#pragma unroll
            for (int rr = 0; rr < 4; ++rr) {
                float v = ((float)accPV[g][rr] - cs4[rr] * za - rs_a * zv + zz) * sav;
                ov[rr] = v;
                vmn = fminf(vmn, v); vmx = fmaxf(vmx, v);
            }
            *(v4f*)(out_mat + obase + d4) = ov;
        }
    }
    __syncthreads();
    red[tid] = vmx; __syncthreads();
    for (int s = 128; s > 0; s >>= 1) { if (tid < s) red[tid] = fmaxf(red[tid], red[tid + s]); __syncthreads(); }
    if (tid == 0) atomicMax(&scal[2 * P_O + 1], encf(red[0]));
    __syncthreads();
    red[tid] = vmn; __syncthreads();
    for (int s = 128; s > 0; s >>= 1) { if (tid < s) red[tid] = fminf(red[tid], red[tid + s]); __syncthreads(); }
    if (tid == 0) atomicMin(&scal[2 * P_O], encf(red[0]));
}

// ---------- launch ----------
extern "C" void kernel_launch(void* const* d_in, const int* in_sizes, int n_in,
                              void* d_out, int out_size, void* d_ws, size_t ws_size,
                              hipStream_t stream) {
    const float* x     = (const float*)d_in[0];
    const float* w_qkv = (const float*)d_in[1];
    const float* w_out = (const float*)d_in[2];
    const float* b_out = (const float*)d_in[3];

    char* ws = (char*)d_ws;
    size_t off = 0;
    auto alloc = [&](size_t n) -> char* {
        char* p = ws + off;
        off = (off + n + 255) & ~(size_t)255;
        return p;
    };
    unsigned*    scal        = (unsigned*)alloc(64);
    float*       xqkv        = (float*)alloc((size_t)Mm * I3 * 4);
    float*       out_mat     = (float*)alloc((size_t)Mm * Dm * 4);
    signed char* xq          = (signed char*)alloc((size_t)Mm * Dm);
    signed char* wq          = (signed char*)alloc((size_t)I3 * Dm);
    signed char* w2q         = (signed char*)alloc((size_t)Dm * Dm);
    signed char* oq          = (signed char*)alloc((size_t)Mm * Dm);
    signed char* qq          = (signed char*)alloc((size_t)BHt * Nn * DH);
    signed char* kq          = (signed char*)alloc((size_t)BHt * Nn * DH);
    signed char* vqT         = (signed char*)alloc((size_t)BHt * Nn * DH);
    float*       rowsum_xq   = (float*)alloc((size_t)Mm * 4);
    float*       colsum_w1   = (float*)alloc((size_t)I3 * 4);
    float*       colsum_w2   = (float*)alloc((size_t)Dm * 4);
    float*       rowsum_xqkv = (float*)alloc((size_t)Mm * 4);
    float*       rowsum_qq   = (float*)alloc((size_t)BHt * Nn * 4);
    float*       cskc        = (float*)alloc((size_t)BHt * Nn * 4);
    float*       colsum_vq   = (float*)alloc((size_t)BHt * DH * 4);
    float*       rowmax      = (float*)alloc((size_t)BHt * Nn * 4);
    float*       sumexp      = (float*)alloc((size_t)BHt * Nn * 4);

    k_init<<<28, 256, 0, stream>>>(scal, rowsum_xqkv, Mm, colsum_vq, BHt * DH);

    k_minmax3<<<448, 256, 0, stream>>>(x, w_qkv, w_out, scal);
    k_quant3<<<7168, 256, 0, stream>>>(x, w_qkv, w_out, scal, xq, wq, w2q,
                                       rowsum_xq, colsum_w1, colsum_w2);

    {   // GEMM1 + fused xqkv row sums and Q/K/V minmax
        dim3 g(I3 / 128, Mm / 128);
        k_gemm_mfma<<<g, 256, 0, stream>>>(xq, wq, colsum_w1, rowsum_xq, nullptr, xqkv,
                                           Dm, I3, scal, P_X, P_W1, 768.0f,
                                           1, rowsum_xqkv, scal);
    }

    k_quant_qkv2<<<BHt * 16, 256, 0, stream>>>(xqkv, scal, qq, kq, vqT,
                                               rowsum_qq, cskc, colsum_vq);

    k_attn_a8<<<BHt * 32, 256, 0, stream>>>(qq, kq, rowsum_qq, cskc, scal, rowmax, sumexp);
    k_attn_b8<<<BHt * 32, 256, 0, stream>>>(qq, kq, vqT, rowsum_qq, cskc, colsum_vq,
                                            rowmax, sumexp, scal, out_mat);

    k_quant_rows<<<Mm, 256, 0, stream>>>(out_mat, scal, P_O, oq);

    {   // GEMM2 (+bias)
        dim3 g(Dm / 128, Mm / 128);
        k_gemm_mfma<<<g, 256, 0, stream>>>(oq, w2q, colsum_w2, rowsum_xqkv, b_out, (float*)d_out,
                                           Dm, Dm, scal, P_O, P_W2, 2304.0f,
                                           0, nullptr, nullptr);
    }
}

// Round 9
// 253.061 us; speedup vs baseline: 1.1268x; 1.1268x over previous
//
#include <hip/hip_runtime.h>
#include <math.h>

#define HEADS 12
#define DH    64
#define Dm    768
#define I3    2304
#define Nn    1024
#define Mm    4096
#define BHt   48
#define LOG2E 1.4426950408889634f

// minmax pair indices
#define P_X  0
#define P_W1 1
#define P_Q  2
#define P_K  3
#define P_V  4
#define P_A  5
#define P_O  6
#define P_W2 7

typedef int   v4i __attribute__((ext_vector_type(4)));
typedef float v4f __attribute__((ext_vector_type(4)));

#if __has_builtin(__builtin_amdgcn_exp2f)
#define EXP2(x) __builtin_amdgcn_exp2f(x)
#else
#define EXP2(x) exp2f(x)
#endif

// ---------- helpers ----------
__device__ inline unsigned encf(float f) {
    unsigned u = __float_as_uint(f);
    return (u & 0x80000000u) ? ~u : (u | 0x80000000u);
}
__device__ inline float decf(unsigned u) {
    return (u & 0x80000000u) ? __uint_as_float(u & 0x7fffffffu) : __uint_as_float(~u);
}
__device__ inline void get_sz(const unsigned* scal, int pair, float* s, float* z) {
    float mn = decf(scal[2 * pair]);
    float mx = decf(scal[2 * pair + 1]);
    float ss = (mx - mn) / 15.0f;
    *s = ss;
    *z = rintf(15.0f - mx / ss);
}

// XCD head-clustering swizzle for attention grids (BHt*16 blocks, dispatch round-robins
// XCD = blk % 8): all 16 itiles of a head land on ONE XCD -> its K/V are fetched from
// HBM once per chip (FETCH 27->5 MB, measured r5) and are L2 hits thereafter.
__device__ inline void swz_bh(int blk, int* bh, int* itile) {
    int xcd = blk & 7, idx = blk >> 3;
    *itile = idx & 15;
    *bh = xcd + 8 * (idx >> 4);
}

// ---------- kernels ----------
// init scal + zero rowsum_xqkv (4096) and colsum_vq (3072)
__global__ __launch_bounds__(256) void k_init(unsigned* scal, float* z1, int n1, float* z2, int n2) {
    int g = blockIdx.x * 256 + threadIdx.x;
    if (g < n1) z1[g] = 0.f;
    if (g < n2) z2[g] = 0.f;
    if (g < 8) { scal[2 * g] = 0xFFFFFFFFu; scal[2 * g + 1] = 0u; }
}

// fused minmax of x (4096x768), w_qkv (2304x768), w_out (768x768); all cols=768
__global__ __launch_bounds__(256) void k_minmax3(const float* x, const float* w1, const float* w2,
                                                 unsigned* scal) {
    __shared__ float rmn[256], rmx[256];
    int bid = blockIdx.x, tid = threadIdx.x;
    const float* src; int rows, pair, b0, nb;
    if (bid < 256)      { src = x;  rows = 4096; pair = P_X;  b0 = 0;   nb = 256; }
    else if (bid < 384) { src = w1; rows = 2304; pair = P_W1; b0 = 256; nb = 128; }
    else                { src = w2; rows = 768;  pair = P_W2; b0 = 384; nb = 64;  }
    float mn = INFINITY, mx = -INFINITY;
    for (int r = bid - b0; r < rows; r += nb) {
        const float* row = src + (long)r * 768;
#pragma unroll
        for (int k = 0; k < 3; ++k) {
            float v = row[tid + k * 256];
            mn = fminf(mn, v); mx = fmaxf(mx, v);
        }
    }
    rmn[tid] = mn; rmx[tid] = mx; __syncthreads();
    for (int s = 128; s > 0; s >>= 1) {
        if (tid < s) { rmn[tid] = fminf(rmn[tid], rmn[tid + s]); rmx[tid] = fmaxf(rmx[tid], rmx[tid + s]); }
        __syncthreads();
    }
    if (tid == 0) {
        atomicMin(&scal[2 * pair], encf(rmn[0]));
        atomicMax(&scal[2 * pair + 1], encf(rmx[0]));
    }
}

// fused quantization of x / w_qkv / w_out (cols=768) -> int8 + row sums
__global__ __launch_bounds__(256) void k_quant3(const float* x, const float* w1, const float* w2,
                                                const unsigned* scal,
                                                signed char* xq, signed char* wq, signed char* w2q,
                                                float* rs_x, float* rs_w1, float* rs_w2) {
    __shared__ float red[256];
    int bid = blockIdx.x, tid = threadIdx.x;
    const float* src; signed char* dq; float* rs; int pair, r;
    if (bid < 4096)      { src = x;  dq = xq;  rs = rs_x;  pair = P_X;  r = bid; }
    else if (bid < 6400) { src = w1; dq = wq;  rs = rs_w1; pair = P_W1; r = bid - 4096; }
    else                 { src = w2; dq = w2q; rs = rs_w2; pair = P_W2; r = bid - 6400; }
    float s, z; get_sz(scal, pair, &s, &z);
    const float* row = src + (long)r * 768;
    signed char* drow = dq + (long)r * 768;
    float acc = 0.f;
#pragma unroll
    for (int k = 0; k < 3; ++k) {
        int c = tid + k * 256;
        float q = rintf(row[c] / s + z);
        drow[c] = (signed char)(int)q;
        acc += q;
    }
    red[tid] = acc; __syncthreads();
    for (int s2 = 128; s2 > 0; s2 >>= 1) { if (tid < s2) red[tid] += red[tid + s2]; __syncthreads(); }
    if (tid == 0) rs[r] = red[0];
}

// MFMA int8 GEMM, block tile 128x128, BK=64 bytes, LDS-staged with register double-buffer.
// Used for GEMM1 (int8 A input).
__global__ __launch_bounds__(256) void k_gemm_mfma(const signed char* A, const signed char* B,
                                                   const float* colsumB, const float* rowsumA,
                                                   const float* bias, float* C, int K, int ldC,
                                                   const unsigned* scal, int pairA, int pairB,
                                                   float corrK, int do_stats, float* rowsum_out,
                                                   unsigned* scal_mm) {
    __shared__ __align__(16) signed char As[128 * 64];
    __shared__ __align__(16) signed char Bs[128 * 64];
    __shared__ float red[256];
    int tid = threadIdx.x;
    int wave = tid >> 6, lane = tid & 63;
    int col16 = lane & 15, quad = lane >> 4;
    long rowbase = (long)blockIdx.y * 128;
    long colbase = (long)blockIdx.x * 128;

    int c4 = tid & 3, r4 = tid >> 2;
    const signed char* ag0 = A + (rowbase + r4) * K + c4 * 16;
    const signed char* ag1 = A + (rowbase + r4 + 64) * K + c4 * 16;
    const signed char* bg0 = B + (colbase + r4) * K + c4 * 16;
    const signed char* bg1 = B + (colbase + r4 + 64) * K + c4 * 16;
    int soff0 = ((r4 >> 4) << 10) + (c4 << 8) + ((r4 & 15) << 4);
    int soff1 = soff0 + 4096;

    v4i ra0 = *(const v4i*)ag0;
    v4i ra1 = *(const v4i*)ag1;
    v4i rb0 = *(const v4i*)bg0;
    v4i rb1 = *(const v4i*)bg1;

    const int afrag_off = wave * 2048 + quad * 256 + col16 * 16;
    const int bfrag_off = quad * 256 + col16 * 16;
    v4i acc[2][8] = {};
    int nk = K >> 6;
    for (int kt = 0; kt < nk; ++kt) {
        *(v4i*)(As + soff0) = ra0;
        *(v4i*)(As + soff1) = ra1;
        *(v4i*)(Bs + soff0) = rb0;
        *(v4i*)(Bs + soff1) = rb1;
        __syncthreads();
        if (kt + 1 < nk) {
            int ko = (kt + 1) << 6;
            ra0 = *(const v4i*)(ag0 + ko);
            ra1 = *(const v4i*)(ag1 + ko);
            rb0 = *(const v4i*)(bg0 + ko);
            rb1 = *(const v4i*)(bg1 + ko);
        }
        v4i af0 = *(const v4i*)(As + afrag_off);
        v4i af1 = *(const v4i*)(As + afrag_off + 1024);
        v4i bf[8];
#pragma unroll
        for (int g = 0; g < 8; ++g) bf[g] = *(const v4i*)(Bs + bfrag_off + g * 1024);
#pragma unroll
        for (int g = 0; g < 8; ++g) {
            acc[0][g] = __builtin_amdgcn_mfma_i32_16x16x64_i8(af0, bf[g], acc[0][g], 0, 0, 0);
            acc[1][g] = __builtin_amdgcn_mfma_i32_16x16x64_i8(af1, bf[g], acc[1][g], 0, 0, 0);
        }
        __syncthreads();
    }

    float sA, zA, sB, zB;
    get_sz(scal, pairA, &sA, &zA);
    get_sz(scal, pairB, &sB, &zB);
    float sAB = sA * sB;
    float zz = (zA * zB) * corrK;
    float vmn = INFINITY, vmx = -INFINITY;
    float rowpart[2][4] = {};
#pragma unroll
    for (int i2 = 0; i2 < 2; ++i2)
#pragma unroll
        for (int g = 0; g < 8; ++g) {
            long col = colbase + g * 16 + col16;
            float cs = colsumB[col] * zA;
            float bv = bias ? bias[col] : 0.f;
#pragma unroll
            for (int r = 0; r < 4; ++r) {
                long row = rowbase + wave * 32 + i2 * 16 + quad * 4 + r;
                float v = ((float)acc[i2][g][r] - cs - rowsumA[row] * zB + zz) * sAB + bv;
                C[row * ldC + col] = v;
                rowpart[i2][r] += v;
                vmn = fminf(vmn, v); vmx = fmaxf(vmx, v);
            }
        }
    if (do_stats) {
#pragma unroll
        for (int i2 = 0; i2 < 2; ++i2)
#pragma unroll
            for (int r = 0; r < 4; ++r) {
                float s = rowpart[i2][r];
                s += __shfl_xor(s, 1); s += __shfl_xor(s, 2);
                s += __shfl_xor(s, 4); s += __shfl_xor(s, 8);
                if (col16 == 0)
                    atomicAdd(&rowsum_out[rowbase + wave * 32 + i2 * 16 + quad * 4 + r], s);
            }
        int pair = P_Q + (int)(colbase / 768);
        red[tid] = vmx; __syncthreads();
        for (int s = 128; s > 0; s >>= 1) { if (tid < s) red[tid] = fmaxf(red[tid], red[tid + s]); __syncthreads(); }
        if (tid == 0) atomicMax(&scal_mm[2 * pair + 1], encf(red[0]));
        __syncthreads();
        red[tid] = vmn; __syncthreads();
        for (int s = 128; s > 0; s >>= 1) { if (tid < s) red[tid] = fminf(red[tid], red[tid + s]); __syncthreads(); }
        if (tid == 0) atomicMin(&scal_mm[2 * pair], encf(red[0]));
    }
}

// GEMM2 with FUSED on-the-fly quantization of A (out_mat, fp32) using the P_O scale —
// replaces k_quant_rows + int8-A GEMM2. Per staging step: load 16 fp32, quantize
// rintf(fmaf(v, 1/s, z)) (rcp-vs-div ulp flips are worth ~1e-3 in the output, far under
// tolerance; oq row sums were never needed — GEMM2's row correction uses rowsum_xqkv).
// Saves a kernel launch + ~18 MB of HBM traffic (oq write + read, out_mat re-read).
__global__ __launch_bounds__(256) void k_gemm2f(const float* A, const signed char* B,
                                                const float* colsumB, const float* rowsumA,
                                                const float* bias, float* C,
                                                const unsigned* scal) {
    __shared__ __align__(16) signed char As[128 * 64];
    __shared__ __align__(16) signed char Bs[128 * 64];
    int tid = threadIdx.x;
    int wave = tid >> 6, lane = tid & 63;
    int col16 = lane & 15, quad = lane >> 4;
    long rowbase = (long)blockIdx.y * 128;
    long colbase = (long)blockIdx.x * 128;

    float sA, zA, sB, zB;
    get_sz(scal, P_O, &sA, &zA);
    get_sz(scal, P_W2, &sB, &zB);
    float rcpA = 1.0f / sA;

    int c4 = tid & 3, r4 = tid >> 2;
    const float* ag0 = A + (rowbase + r4) * 768 + c4 * 16;
    const float* ag1 = A + (rowbase + r4 + 64) * 768 + c4 * 16;
    const signed char* bg0 = B + (colbase + r4) * 768 + c4 * 16;
    const signed char* bg1 = B + (colbase + r4 + 64) * 768 + c4 * 16;
    int soff0 = ((r4 >> 4) << 10) + (c4 << 8) + ((r4 & 15) << 4);
    int soff1 = soff0 + 4096;

    v4f fa0[4], fa1[4];
#pragma unroll
    for (int j = 0; j < 4; ++j) {
        fa0[j] = *(const v4f*)(ag0 + j * 4);
        fa1[j] = *(const v4f*)(ag1 + j * 4);
    }
    v4i rb0 = *(const v4i*)bg0;
    v4i rb1 = *(const v4i*)bg1;

    const int afrag_off = wave * 2048 + quad * 256 + col16 * 16;
    const int bfrag_off = quad * 256 + col16 * 16;
    v4i acc[2][8] = {};
    for (int kt = 0; kt < 12; ++kt) {
        v4i qa0, qa1;
#pragma unroll
        for (int j = 0; j < 4; ++j) {
            unsigned w0 = 0, w1 = 0;
#pragma unroll
            for (int e = 0; e < 4; ++e) {
                float q0 = rintf(fmaf(fa0[j][e], rcpA, zA));
                float q1 = rintf(fmaf(fa1[j][e], rcpA, zA));
                w0 |= ((unsigned)(int)q0 & 255u) << (8 * e);
                w1 |= ((unsigned)(int)q1 & 255u) << (8 * e);
            }
            qa0[j] = (int)w0;
            qa1[j] = (int)w1;
        }
        *(v4i*)(As + soff0) = qa0;
        *(v4i*)(As + soff1) = qa1;
        *(v4i*)(Bs + soff0) = rb0;
        *(v4i*)(Bs + soff1) = rb1;
        __syncthreads();
        if (kt + 1 < 12) {
            int ko = (kt + 1) << 6;
#pragma unroll
            for (int j = 0; j < 4; ++j) {
                fa0[j] = *(const v4f*)(ag0 + ko + j * 4);
                fa1[j] = *(const v4f*)(ag1 + ko + j * 4);
            }
            rb0 = *(const v4i*)(bg0 + ko);
            rb1 = *(const v4i*)(bg1 + ko);
        }
        v4i af0 = *(const v4i*)(As + afrag_off);
        v4i af1 = *(const v4i*)(As + afrag_off + 1024);
        v4i bf[8];
#pragma unroll
        for (int g = 0; g < 8; ++g) bf[g] = *(const v4i*)(Bs + bfrag_off + g * 1024);
#pragma unroll
        for (int g = 0; g < 8; ++g) {
            acc[0][g] = __builtin_amdgcn_mfma_i32_16x16x64_i8(af0, bf[g], acc[0][g], 0, 0, 0);
            acc[1][g] = __builtin_amdgcn_mfma_i32_16x16x64_i8(af1, bf[g], acc[1][g], 0, 0, 0);
        }
        __syncthreads();
    }

    float sAB = sA * sB;
    float zz = (zA * zB) * 2304.0f;   // faithful: reference uses xqkv width here
#pragma unroll
    for (int i2 = 0; i2 < 2; ++i2)
#pragma unroll
        for (int g = 0; g < 8; ++g) {
            long col = colbase + g * 16 + col16;
            float cs = colsumB[col] * zA;
            float bv = bias[col];
#pragma unroll
            for (int r = 0; r < 4; ++r) {
                long row = rowbase + wave * 32 + i2 * 16 + quad * 4 + r;
                float v = ((float)acc[i2][g][r] - cs - rowsumA[row] * zB + zz) * sAB + bv;
                C[row * 768 + col] = v;
            }
        }
}

// quantize q/k/v, 64 i-rows per block. qq,kq row-contig; vqT via LDS transpose (16B stores).
// cskc[j] = colsum_kq[j]*zq*csc*LOG2E (log2-domain constant), colsum_vq via exact atomicAdd.
__global__ __launch_bounds__(256) void k_quant_qkv2(const float* xqkv, const unsigned* scal,
                                                    signed char* qq, signed char* kq, signed char* vqT,
                                                    float* rowsum_qq, float* cskc, float* colsum_vq) {
    __shared__ __align__(16) signed char vt[64 * 80];   // [d][i_local], stride 80
    __shared__ float vred[4][64];
    int blk = blockIdx.x;
    int bh = blk >> 4, itile = blk & 15;
    int tid = threadIdx.x;
    int wave = tid >> 6, d = tid & 63;
    int b = bh / HEADS, h = bh - HEADS * b;
    float sq, zq, sk, zk, sv, zv;
    get_sz(scal, P_Q, &sq, &zq);
    get_sz(scal, P_K, &sk, &zk);
    get_sz(scal, P_V, &sv, &zv);
    float zqcsc2 = zq * ((0.125f * sq) * sk) * LOG2E;
    int vb = 0;
    float vsum = 0.f;
    for (int ir = 0; ir < 16; ++ir) {
        int il = wave * 16 + ir;
        int i = itile * 64 + il;
        const float* row = xqkv + ((long)b * Nn + i) * I3 + h * DH;
        float q = rintf(row[d] / sq + zq);
        float k = rintf(row[768 + d] / sk + zk);
        float v = rintf(row[1536 + d] / sv + zv);
        long o = ((long)bh * Nn + i) * 64 + d;
        qq[o] = (signed char)(int)q;
        kq[o] = (signed char)(int)k;
        vsum += v;
        vb |= ((int)v & 0xff) << ((ir & 3) * 8);
        if ((ir & 3) == 3) {
            *(int*)(vt + d * 80 + (il & ~3)) = vb;
            vb = 0;
        }
        float s1 = q, s2 = k;
        for (int off = 32; off > 0; off >>= 1) {
            s1 += __shfl_down(s1, off);
            s2 += __shfl_down(s2, off);
        }
        if (d == 0) { rowsum_qq[bh * Nn + i] = s1; cskc[bh * Nn + i] = s2 * zqcsc2; }
    }
    vred[wave][d] = vsum;
    __syncthreads();
    int dd = tid >> 2, c = tid & 3;
    *(v4i*)(vqT + ((long)bh * 64 + dd) * 1024 + itile * 64 + c * 16) = *(const v4i*)(vt + dd * 80 + c * 16);
    if (tid < 64)   // exact: integer-valued floats, order-free
        atomicAdd(&colsum_vq[bh * 64 + tid],
                  ((vred[0][tid] + vred[1][tid]) + vred[2][tid]) + vred[3][tid]);
}

// Pass A v13 (= round-1 v9 + XCD head-clustering swizzle): 64 q-rows/block, online
// softmax in LOG2 domain, K+ck register double-buffer prefetch, single-EXP2 update.
__global__ __launch_bounds__(256) void k_attn_a8(const signed char* qq, const signed char* kq,
                                                 const float* rowsum_qq, const float* cskc,
                                                 unsigned* scal, float* rowmax, float* sumexp) {
    __shared__ float red[256];
    int bh, itile;
    swz_bh(blockIdx.x, &bh, &itile);
    int tid = threadIdx.x;
    int wave = tid >> 6, lane = tid & 63;
    int col16 = lane & 15, quad = lane >> 4;
    int rowbase = itile * 64 + wave * 16;
    const signed char* kbase = kq + (long)bh * Nn * 64;
    const float* ck = cskc + bh * Nn;
    v4i afrag = *(const v4i*)(qq + ((long)bh * Nn + rowbase + col16) * 64 + quad * 16);
    float sq, zq, sk, zk;
    get_sz(scal, P_Q, &sq, &zq);
    get_sz(scal, P_K, &sk, &zk);
    float csc2 = ((0.125f * sq) * sk) * LOG2E;
    float rzc[4];
#pragma unroll
    for (int r = 0; r < 4; ++r)
        rzc[r] = rowsum_qq[bh * Nn + rowbase + quad * 4 + r] * zk * csc2;
    v4i zero = {0, 0, 0, 0};
    float m[4]    = {-INFINITY, -INFINITY, -INFINITY, -INFINITY};
    float se[4]   = {0.f, 0.f, 0.f, 0.f};
    float lmin[4] = {INFINITY, INFINITY, INFINITY, INFINITY};
    const signed char* kf = kbase + (long)col16 * 64 + quad * 16;
    const float* ckp = ck + col16;
    v4i kb[2][4];
    float ckc[4], ckn[4];
#pragma unroll
    for (int t = 0; t < 4; ++t) {
        kb[0][t] = *(const v4i*)(kf + (long)(t * 16) * 64);
        ckc[t] = ckp[t * 16];
    }
#pragma unroll 2
    for (int ch = 0; ch < 16; ++ch) {
        int cur = ch & 1, nxt = cur ^ 1;
        int pch = (ch < 15) ? ch + 1 : 15;
#pragma unroll
        for (int t = 0; t < 4; ++t) {
            kb[nxt][t] = *(const v4i*)(kf + (long)(pch * 64 + t * 16) * 64);
            ckn[t] = ckp[pch * 64 + t * 16];
        }
#pragma unroll
        for (int t = 0; t < 4; ++t) {
            v4i d = __builtin_amdgcn_mfma_i32_16x16x64_i8(afrag, kb[cur][t], zero, 0, 0, 0);
            float ckv = ckc[t];
#pragma unroll
            for (int r = 0; r < 4; ++r) {
                float dv = fmaf((float)d[r], csc2, -(ckv + rzc[r]));
                lmin[r] = fminf(lmin[r], dv);
                float mn = fmaxf(m[r], dv);
                // single-EXP2 online update, bit-identical to:
                //   se = fmaf(se, EXP2(m-mn), EXP2(dv-mn))
                float e = EXP2(fminf(m[r], dv) - mn);
                se[r] = (dv > m[r]) ? fmaf(se[r], e, 1.0f) : (se[r] + e);
                m[r] = mn;
            }
        }
#pragma unroll
        for (int t = 0; t < 4; ++t) ckc[t] = ckn[t];
    }
#pragma unroll
    for (int r = 0; r < 4; ++r) {
#pragma unroll
        for (int off = 1; off < 16; off <<= 1) {
            float mo = __shfl_xor(m[r], off);
            float so = __shfl_xor(se[r], off);
            float mino = __shfl_xor(lmin[r], off);
            float mn = fmaxf(m[r], mo);
            se[r] = fmaf(se[r], EXP2(m[r] - mn), so * EXP2(mo - mn));
            m[r] = mn;
            lmin[r] = fminf(lmin[r], mino);
        }
    }
    float amax_c = -INFINITY, amin_c = INFINITY;
    if (col16 == 0) {
#pragma unroll
        for (int r = 0; r < 4; ++r) {
            int grow = bh * Nn + rowbase + quad * 4 + r;
            rowmax[grow] = m[r];          // log2 units
            sumexp[grow] = se[r];
            amax_c = fmaxf(amax_c, 1.0f / se[r]);
            amin_c = fminf(amin_c, EXP2(lmin[r] - m[r]) / se[r]);
        }
    }
    red[tid] = amax_c; __syncthreads();
    for (int s = 128; s > 0; s >>= 1) { if (tid < s) red[tid] = fmaxf(red[tid], red[tid + s]); __syncthreads(); }
    if (tid == 0) atomicMax(&scal[2 * P_A + 1], encf(red[0]));
    __syncthreads();
    red[tid] = amin_c; __syncthreads();
    for (int s = 128; s > 0; s >>= 1) { if (tid < s) red[tid] = fminf(red[tid], red[tid + s]); __syncthreads(); }
    if (tid == 0) atomicMin(&scal[2 * P_A], encf(red[0]));
}

// Pass B v13 + T5 setprio: K/ck register double-buffer prefetch (2-chunk distance),
// XOR-swizzled LDS quant round-trip, x2-unrolled main loop, XCD head-clustering.
// s_setprio(1) around the PV MFMA cluster: barrier-free loop = waves at independent
// phases, the condition where setprio measured +4-7% on attention (m191).
__global__ __launch_bounds__(256) void k_attn_b8(const signed char* qq, const signed char* kq,
                                                 const signed char* vqT, const float* rowsum_qq,
                                                 const float* cskc, const float* colsum_vq,
                                                 const float* rowmax, const float* sumexp,
                                                 unsigned* scal, float* out_mat) {
    __shared__ __align__(16) signed char AqB[8192];
    __shared__ float red[256];
    int bh, itile;
    swz_bh(blockIdx.x, &bh, &itile);
    int tid = threadIdx.x;
    int wave = tid >> 6, lane = tid & 63;
    int col16 = lane & 15, quad = lane >> 4;
    int rowbase = itile * 64 + wave * 16;
    int b = bh / HEADS, h = bh - HEADS * b;
    const signed char* kbase = kq + (long)bh * Nn * 64;
    const signed char* vbase = vqT + (long)bh * 64 * 1024;
    const float* ck = cskc + bh * Nn;
    v4i afrag = *(const v4i*)(qq + ((long)bh * Nn + rowbase + col16) * 64 + quad * 16);
    float sq, zq, sk, zk, sv, zv, sa, za;
    get_sz(scal, P_Q, &sq, &zq);
    get_sz(scal, P_K, &sk, &zk);
    get_sz(scal, P_V, &sv, &zv);
    get_sz(scal, P_A, &sa, &za);
    float csc2 = ((0.125f * sq) * sk) * LOG2E;
    float roff[4], crcp[4];
#pragma unroll
    for (int r = 0; r < 4; ++r) {
        int row = bh * Nn + rowbase + quad * 4 + r;
        roff[r] = rowsum_qq[row] * zk * csc2 + rowmax[row];   // log2 units
        crcp[r] = 1.0f / (sumexp[row] * sa);
    }
    v4i accPV[4] = {};
    float rs_a[4] = {0.f, 0.f, 0.f, 0.f};
    v4i zero = {0, 0, 0, 0};
    const signed char* kf = kbase + (long)col16 * 64 + quad * 16;
    const float* ckp = ck + col16;
    // swizzled LDS read offset for the PV A-fragment (row=col16, bytes quad*16..+15)
    const int pa_off = wave * 1024 + col16 * 64 + ((quad ^ (col16 >> 2)) << 4);

    // K-fragment + ck double-buffer registers (chunk c lives in buffer c&1)
    v4i kb0[4], kb1[4];
    float ckr0[4], ckr1[4];
#pragma unroll
    for (int t = 0; t < 4; ++t) {
        kb0[t] = *(const v4i*)(kf + (long)(t * 16) * 64);
        ckr0[t] = ckp[t * 16];
        kb1[t] = *(const v4i*)(kf + (long)(64 + t * 16) * 64);
        ckr1[t] = ckp[64 + t * 16];
    }

    // quantize chunk into LDS buffer BUF using preloaded K frags KB / ck regs CKR.
    // store swizzle: byte (rr=quad*4+r, c=t*16+col16) -> rr*64 + ((t^quad)<<4) + col16
#define QUANT_CHUNK(BUF, KB, CKR)                                                       \
    {                                                                                   \
        signed char* myAq = AqB + (BUF) * 4096 + wave * 1024;                           \
        _Pragma("unroll")                                                               \
        for (int t = 0; t < 4; ++t) {                                                   \
            v4i d = __builtin_amdgcn_mfma_i32_16x16x64_i8(afrag, KB[t], zero, 0, 0, 0); \
            float ckv = CKR[t];                                                         \
            int cswz = ((t ^ quad) << 4) + col16;                                       \
            _Pragma("unroll")                                                           \
            for (int r = 0; r < 4; ++r) {                                               \
                float es = fmaf((float)d[r], csc2, -(ckv + roff[r]));                   \
                float fastv = fmaf(EXP2(es), crcp[r], za);                              \
                float aqv = rintf(fastv);                                               \
                rs_a[r] += aqv;                                                         \
                myAq[(quad * 4 + r) * 64 + cswz] = (signed char)(int)aqv;               \
            }                                                                           \
        }                                                                               \
    }

    // one main-loop iteration: chunk CH (buffer CUR). Prefetch K/ck for chunk CH+2
    // into the CUR-parity buffer (dead since last iteration), quantize chunk CH+1
    // (buffer 1-CUR, K frags preloaded last iteration), then PV MFMA for chunk CH.
#define BODY(CH, CUR, KBc, CKc, KBn, CKn)                                               \
    {                                                                                   \
        v4i pa = *(const v4i*)(AqB + (CUR) * 4096 + pa_off);                            \
        v4i bv[4];                                                                      \
        _Pragma("unroll")                                                               \
        for (int g = 0; g < 4; ++g)                                                     \
            bv[g] = *(const v4i*)(vbase + (long)(g * 16 + col16) * 1024 + (CH) * 64 + quad * 16); \
        if ((CH) < 14) {                                                                \
            _Pragma("unroll")                                                           \
            for (int t = 0; t < 4; ++t) {                                               \
                KBc[t] = *(const v4i*)(kf + (long)(((CH) + 2) * 64 + t * 16) * 64);     \
                CKc[t] = ckp[((CH) + 2) * 64 + t * 16];                                 \
            }                                                                           \
        }                                                                               \
        if ((CH) < 15) QUANT_CHUNK(1 - (CUR), KBn, CKn)                                 \
        __builtin_amdgcn_s_setprio(1);                                                  \
        _Pragma("unroll")                                                               \
        for (int g = 0; g < 4; ++g)                                                     \
            accPV[g] = __builtin_amdgcn_mfma_i32_16x16x64_i8(pa, bv[g], accPV[g], 0, 0, 0); \
        __builtin_amdgcn_s_setprio(0);                                                  \
    }

    QUANT_CHUNK(0, kb0, ckr0)
    for (int ch2 = 0; ch2 < 8; ++ch2) {
        int ch = ch2 * 2;
        BODY(ch, 0, kb0, ckr0, kb1, ckr1)
        BODY(ch + 1, 1, kb1, ckr1, kb0, ckr0)
    }
#undef BODY
#undef QUANT_CHUNK

#pragma unroll
    for (int r = 0; r < 4; ++r)
        for (int off = 1; off < 16; off <<= 1) rs_a[r] += __shfl_xor(rs_a[r], off);
    float sav = sa * sv;
    float zz = (za * zv) * 1024.0f;
    float vmn = INFINITY, vmx = -INFINITY;
#pragma unroll
    for (int g = 0; g < 4; ++g) {
        int d = g * 16 + col16;
        float cs = colsum_vq[bh * 64 + d] * za;
#pragma unroll
        for (int r = 0; r < 4; ++r) {
            int i = rowbase + quad * 4 + r;
            float v = ((float)accPV[g][r] - cs - rs_a[r] * zv + zz) * sav;
            out_mat[((long)b * Nn + i) * Dm + h * DH + d] = v;
            vmn = fminf(vmn, v); vmx = fmaxf(vmx, v);
        }
    }
    red[tid] = vmx; __syncthreads();
    for (int s = 128; s > 0; s >>= 1) { if (tid < s) red[tid] = fmaxf(red[tid], red[tid + s]); __syncthreads(); }
    if (tid == 0) atomicMax(&scal[2 * P_O + 1], encf(red[0]));
    __syncthreads();
    red[tid] = vmn; __syncthreads();
    for (int s = 128; s > 0; s >>= 1) { if (tid < s) red[tid] = fminf(red[tid], red[tid + s]); __syncthreads(); }
    if (tid == 0) atomicMin(&scal[2 * P_O], encf(red[0]));
}

// ---------- launch ----------
extern "C" void kernel_launch(void* const* d_in, const int* in_sizes, int n_in,
                              void* d_out, int out_size, void* d_ws, size_t ws_size,
                              hipStream_t stream) {
    const float* x     = (const float*)d_in[0];
    const float* w_qkv = (const float*)d_in[1];
    const float* w_out = (const float*)d_in[2];
    const float* b_out = (const float*)d_in[3];

    char* ws = (char*)d_ws;
    size_t off = 0;
    auto alloc = [&](size_t n) -> char* {
        char* p = ws + off;
        off = (off + n + 255) & ~(size_t)255;
        return p;
    };
    unsigned*    scal        = (unsigned*)alloc(64);
    float*       xqkv        = (float*)alloc((size_t)Mm * I3 * 4);
    float*       out_mat     = (float*)alloc((size_t)Mm * Dm * 4);
    signed char* xq          = (signed char*)alloc((size_t)Mm * Dm);
    signed char* wq          = (signed char*)alloc((size_t)I3 * Dm);
    signed char* w2q         = (signed char*)alloc((size_t)Dm * Dm);
    signed char* qq          = (signed char*)alloc((size_t)BHt * Nn * DH);
    signed char* kq          = (signed char*)alloc((size_t)BHt * Nn * DH);
    signed char* vqT         = (signed char*)alloc((size_t)BHt * Nn * DH);
    float*       rowsum_xq   = (float*)alloc((size_t)Mm * 4);
    float*       colsum_w1   = (float*)alloc((size_t)I3 * 4);
    float*       colsum_w2   = (float*)alloc((size_t)Dm * 4);
    float*       rowsum_xqkv = (float*)alloc((size_t)Mm * 4);
    float*       rowsum_qq   = (float*)alloc((size_t)BHt * Nn * 4);
    float*       cskc        = (float*)alloc((size_t)BHt * Nn * 4);
    float*       colsum_vq   = (float*)alloc((size_t)BHt * DH * 4);
    float*       rowmax      = (float*)alloc((size_t)BHt * Nn * 4);
    float*       sumexp      = (float*)alloc((size_t)BHt * Nn * 4);

    k_init<<<28, 256, 0, stream>>>(scal, rowsum_xqkv, Mm, colsum_vq, BHt * DH);

    k_minmax3<<<448, 256, 0, stream>>>(x, w_qkv, w_out, scal);
    k_quant3<<<7168, 256, 0, stream>>>(x, w_qkv, w_out, scal, xq, wq, w2q,
                                       rowsum_xq, colsum_w1, colsum_w2);

    {   // GEMM1 + fused xqkv row sums and Q/K/V minmax
        dim3 g(I3 / 128, Mm / 128);
        k_gemm_mfma<<<g, 256, 0, stream>>>(xq, wq, colsum_w1, rowsum_xq, nullptr, xqkv,
                                           Dm, I3, scal, P_X, P_W1, 768.0f,
                                           1, rowsum_xqkv, scal);
    }

    k_quant_qkv2<<<BHt * 16, 256, 0, stream>>>(xqkv, scal, qq, kq, vqT,
                                               rowsum_qq, cskc, colsum_vq);

    k_attn_a8<<<BHt * 16, 256, 0, stream>>>(qq, kq, rowsum_qq, cskc, scal, rowmax, sumexp);
    k_attn_b8<<<BHt * 16, 256, 0, stream>>>(qq, kq, vqT, rowsum_qq, cskc, colsum_vq,
                                            rowmax, sumexp, scal, out_mat);

    {   // GEMM2 with fused A-quantization (+bias) — replaces k_quant_rows + int8 GEMM2
        dim3 g(Dm / 128, Mm / 128);
        k_gemm2f<<<g, 256, 0, stream>>>(out_mat, w2q, colsum_w2, rowsum_xqkv, b_out,
                                        (float*)d_out, scal);
    }
}